// Round 1
// 237.949 us; speedup vs baseline: 1.0634x; 1.0634x over previous
//
#include <hip/hip_runtime.h>
#include <stdint.h>

// Fused Guided_Conv (B=16,H=W=384,F=9,P=24,KS=3, NB=4096 patches).
// R1: fuse kgl+apply. Dependency is block-local (apply patch m reads only
// weights generated from guidance patch m) -> generated weights stay in LDS
// (sw[216]); no ws round-trip, one dispatch instead of two.
// sd/sg layout: linear [24][24][9]. Pixel stride = 9 words, coprime with the
// 32 LDS banks -> conflict-free scalar reads (old [26][26][12] halo = 48B
// stride = 8-way conflicts, 5.5M conflict cycles/dispatch). Halo replaced by
// predicated taps (per-patch SAME conv zero-pads).
// Staging: __builtin_amdgcn_global_load_lds width=16 — async direct
// global->LDS; LDS dest is wave-uniform base + lane*16, which matches the
// linear task order exactly (task = first_task_of_wave + lane).

__device__ __forceinline__ void gload16(const float* gsrc, float* ldst) {
    __builtin_amdgcn_global_load_lds(
        (__attribute__((address_space(1))) void*)gsrc,
        (__attribute__((address_space(3))) void*)ldst, 16, 0, 0);
}

__global__ __launch_bounds__(576, 6) void fused_kernel(
    const float* __restrict__ g,
    const float* __restrict__ dep,
    const float* __restrict__ cw,
    const float* __restrict__ cb,
    const float* __restrict__ dw,
    const float* __restrict__ db,
    float* __restrict__ out)
{
    __shared__ __align__(16) float sg[5184];   // guidance patch [24][24][9]
    __shared__ __align__(16) float sd[5184];   // depth patch    [24][24][9]
    __shared__ __align__(16) float cwf[729];   // conv_w [du][dv][ci][o]
    __shared__ __align__(16) float dwf[729];   // dense_w [k][81]
    __shared__ float cbf[9];
    __shared__ float dbf[81];
    __shared__ float cols[216];                // per-(col,f) sums over rows
    __shared__ float gapm[9];
    __shared__ float cful[81];                 // conv out [uv][o]
    __shared__ __align__(16) float sw[216];    // w1[9][12] + w2t[9][12] (pads unread)

    const int m = blockIdx.x;
    const int t = threadIdx.x;
    const int b0 = m >> 8, pi = (m >> 4) & 15, pj = m & 15;
    const long rowbase = ((long)(b0 * 384 + pi * 24)) * 3456 + (long)pj * 216;

    // ---- Phase 0: async-stage both patches (1296 float4 each) + weights ----
    // tasks are consecutive within each wave -> lds dst = uniform base + lane*16.
    for (int task = t; task < 1296; task += 576) {
        int r = task / 54, c4 = task - r * 54;
        gload16(g + rowbase + (long)r * 3456 + c4 * 4, sg + task * 4);
    }
    for (int task = t; task < 1296; task += 576) {
        int r = task / 54, c4 = task - r * 54;
        gload16(dep + rowbase + (long)r * 3456 + c4 * 4, sd + task * 4);
    }
    for (int idx = t; idx < 729; idx += 576) { cwf[idx] = cw[idx]; dwf[idx] = dw[idx]; }
    if (t < 9) cbf[t] = cb[t];
    if (t >= 64 && t < 145) dbf[t - 64] = db[t - 64];
    __syncthreads();   // compiler drains vmcnt(0) here -> sg/sd resident

    // ---- P1: column sums (t<216)  ||  strided 3x3 conv (81 thr, waves 4-5) ----
    if (t < 216) {
        float s = 0.f;
        #pragma unroll
        for (int r = 0; r < 24; ++r) s += sg[r * 216 + t];
        cols[t] = s;
    } else if (t >= 256 && t < 337) {
        const int q = t - 256;
        const int o = q % 9, uv = q / 9, v = uv % 3, u = uv / 3;
        float acc = cbf[o];
        #pragma unroll
        for (int du = 0; du < 3; ++du)
        #pragma unroll
        for (int dv = 0; dv < 3; ++dv) {
            const float* gp2 = &sg[(u * 8 + du) * 216 + (v * 8 + dv) * 9];
            const float* wp  = &cwf[(du * 3 + dv) * 81 + o];
            #pragma unroll
            for (int ci = 0; ci < 9; ++ci) acc += gp2[ci] * wp[ci * 9];
        }
        cful[q] = acc;
    }
    __syncthreads();

    // ---- P2: GAP (t<9)  ||  W1 clip+store (9 thr, wave 1) ----
    if (t < 9) {
        float s = 0.f;
        #pragma unroll
        for (int c = 0; c < 24; ++c) s += cols[c * 9 + t];
        gapm[t] = s * (1.0f / 576.0f);
    } else if (t >= 64 && t < 73) {
        const int f = t - 64;
        float s = 0.f;
        #pragma unroll
        for (int k = 0; k < 9; ++k) { float c = cful[k * 9 + f]; s += c * c; }
        const float scale = (s > 1.0f) ? (1.0f / sqrtf(s)) : 1.0f;
        #pragma unroll
        for (int k = 0; k < 9; ++k) sw[k * 12 + f] = cful[k * 9 + f] * scale;
    }
    __syncthreads();

    // ---- P3: dense + W2 clip fused (thread t = output o; sums over i) ----
    if (t < 9) {
        float gv[9];
        #pragma unroll
        for (int k = 0; k < 9; ++k) gv[k] = gapm[k];
        float d[9];
        float s = 0.f;
        #pragma unroll
        for (int i = 0; i < 9; ++i) {
            float a = dbf[i * 9 + t];
            #pragma unroll
            for (int k = 0; k < 9; ++k) a += gv[k] * dwf[k * 81 + i * 9 + t];
            d[i] = a; s += a * a;
        }
        const float scale = (s > 1.0f) ? (1.0f / sqrtf(s)) : 1.0f;
        #pragma unroll
        for (int i = 0; i < 9; ++i) sw[108 + t * 12 + i] = d[i] * scale;
    }
    __syncthreads();

    // ---- P4: apply — 1 pixel/thread, predicated taps, conflict-free reads ----
    {
        const int row = t / 24;
        const int col = t - row * 24;
        float dc[9];
        #pragma unroll
        for (int i = 0; i < 9; ++i) dc[i] = 0.f;

        #pragma unroll
        for (int du = 0; du < 3; ++du) {
            const int r = row + du - 1;
            if (r < 0 || r > 23) continue;
            #pragma unroll
            for (int dv = 0; dv < 3; ++dv) {
                const int c = col + dv - 1;
                if (c < 0 || c > 23) continue;
                const float* sp = &sd[r * 216 + c * 9];   // lane stride 9 words: conflict-free
                const float* wv = &sw[(du * 3 + dv) * 12]; // broadcast, 16B-aligned
                #pragma unroll
                for (int i = 0; i < 9; ++i) dc[i] += sp[i] * wv[i];
            }
        }

        float* op = out + (long)m * 5184 + t * 9;
        #pragma unroll
        for (int o = 0; o < 9; ++o) {
            const float* wv = &sw[108 + o * 12];
            float a = 0.f;
            #pragma unroll
            for (int i = 0; i < 9; ++i) a += dc[i] * wv[i];
            op[o] = a;
        }
    }
}

extern "C" void kernel_launch(void* const* d_in, const int* in_sizes, int n_in,
                              void* d_out, int out_size, void* d_ws, size_t ws_size,
                              hipStream_t stream) {
    const float* g  = (const float*)d_in[0];
    const float* dp = (const float*)d_in[1];
    const float* cw = (const float*)d_in[2];
    const float* cb = (const float*)d_in[3];
    const float* dw = (const float*)d_in[4];
    const float* db = (const float*)d_in[5];
    float* out = (float*)d_out;
    (void)d_ws; (void)ws_size;

    fused_kernel<<<dim3(4096), dim3(576), 0, stream>>>(g, dp, cw, cb, dw, db, out);
}